// Round 10
// baseline (232.402 us; speedup 1.0000x reference)
//
#include <hip/hip_runtime.h>
#include <hip/hip_bf16.h>

#define EPS 1e-3f

typedef __attribute__((ext_vector_type(8))) short short8;
typedef __attribute__((ext_vector_type(4))) float v4f;

__device__ __forceinline__ unsigned short f2bf(float f) {
    unsigned int u = __float_as_uint(f);
    unsigned int r = (u + 0x7fffu + ((u >> 16) & 1u)) >> 16;
    return (unsigned short)r;
}

// ---------------------------------------------------------------------------
// Prep: fold biases + BN into per-channel affine; transpose pw_kernel into
// bf16 MFMA B-fragment layout.  (unchanged)
// ---------------------------------------------------------------------------
__global__ __launch_bounds__(256) void prep_kernel(
    const float* __restrict__ dwb,
    const float* __restrict__ g1, const float* __restrict__ b1,
    const float* __restrict__ m1, const float* __restrict__ v1,
    const float* __restrict__ pw, const float* __restrict__ pwb,
    const float* __restrict__ g2, const float* __restrict__ b2,
    const float* __restrict__ m2, const float* __restrict__ v2,
    float* __restrict__ scale1, float* __restrict__ shift1,
    float* __restrict__ s2, float* __restrict__ t2,
    unsigned short* __restrict__ Wt)
{
    int tid = threadIdx.x;
    if (blockIdx.x == 0) {
        if (tid < 64) {
            float inv = g1[tid] * rsqrtf(v1[tid] + EPS);
            scale1[tid] = inv;
            shift1[tid] = dwb[tid] * inv + b1[tid] - m1[tid] * inv;
        }
        if (tid < 128) {
            float inv = g2[tid] * rsqrtf(v2[tid] + EPS);
            s2[tid] = inv;
            t2[tid] = pwb[tid] * inv + b2[tid] - m2[tid] * inv;
        }
    }
    int idx = blockIdx.x * 256 + tid;      // 0..8191
    int j     = idx & 7;
    int lane  = (idx >> 3) & 63;
    int kstep = (idx >> 9) & 1;
    int ntile = idx >> 10;                 // 0..7
    int k = kstep * 32 + (lane >> 4) * 8 + j;
    int f = ntile * 16 + (lane & 15);
    Wt[idx] = f2bf(pw[k * 128 + f]);
}

// ---------------------------------------------------------------------------
// Fused kernel, latency-pipelined v5.
// R9 post-mortem: spill fixed (WRITE=output exactly) but dur flat at ~72us
// and residency pinned ~2 blocks/CU regardless of grid/LDS caps -> the
// occupancy lever is dead.  Wall(72) >> VALU-busy(12us/CU): per-wave exposed
// load latency dominates -- 3 serial {6-load -> wait -> 144 FMA} phases per
// k-iter, with the 110MB output stream evicting x from L2.
// Changes vs R9 (both attack load latency):
//  1. hh-phase software pipeline: two NAMED xv buffers (static indexing),
//     loads of phase hh+1 issued before FMAs of phase hh (+24 VGPR).
//  2. non-temporal output stores: stop trashing L2 with the result stream.
// Structure otherwise identical: DPB=3, grid 1152, direct-global conv,
// yS double-buffer, one barrier per finish-iter, launch_bounds(256,3).
// ---------------------------------------------------------------------------
__global__ __launch_bounds__(256, 3) void fused_kernel(
    const float* __restrict__ x,
    const float* __restrict__ wgt,          // (3,3,3,1,64)
    const float* __restrict__ scale1,
    const float* __restrict__ shift1,
    const unsigned short* __restrict__ Wt,  // bf16 B-fragments (16 KB)
    const float* __restrict__ s2,
    const float* __restrict__ t2,
    float* __restrict__ out)
{
    __shared__ float wS[27 * 64];              // 6912 B
    __shared__ float sS[64];
    __shared__ float tS[64];
    __shared__ float s2S[128];
    __shared__ float t2S[128];
    __shared__ unsigned short yS[2][64 * 72];  // 2 x 9216 B

    int tid = threadIdx.x;
    for (int i = tid; i < 27 * 64; i += 256) wS[i] = wgt[i];
    if (tid < 64) { sS[tid] = scale1[tid]; tS[tid] = shift1[tid]; }
    if (tid < 128) { s2S[tid] = s2[tid]; t2S[tid] = t2[tid]; }
    __syncthreads();

    // XCD-aware decode: 1152 blocks = 8 xcd * 144; each XCD owns 4
    // consecutive bdg groups (contiguous 12-deep d range -> L2-shared halos)
    int n   = blockIdx.x;
    int g   = (n & 7) * 144 + (n >> 3);
    int bdg = g / 36;              // 0..31 = b*16 + dgrp
    int hw  = g % 36;
    int b    = bdg >> 4;
    int dgrp = bdg & 15;
    int d0   = dgrp * 3;
    int w0  = (hw % 3) * 16;
    int h0  = (hw / 3) * 4;

    int tx = tid & 15;            // channel group
    int ty = tid >> 4;            // 0..15
    int c0 = tx * 4;
    int wq = ty & 3;
    int rh = ty >> 2;             // == wave id -> h is wave-uniform

    int wv   = tid >> 6;
    int lane = tid & 63;
    int lrow = lane & 15;
    int quad = lane >> 4;

    // ---- per-thread invariant conv addressing (clamped) ----
    int w0t = w0 + wq * 4;
    float mwL = (w0t >= 1)  ? 1.f : 0.f;   // window p=0 (zw = w0t-1)
    float mwR = (w0t <= 43) ? 1.f : 0.f;   // window p=5 (zw = w0t+4)
    int wcl[6];
    #pragma unroll
    for (int p = 0; p < 6; ++p)
        wcl[p] = min(max(w0t - 1 + p, 0), 47) * 64;

    int h = h0 + rh;
    bool hok[3];
    int  hcl[3];
    #pragma unroll
    for (int hh = 0; hh < 3; ++hh) {
        int zh = h + hh - 1;
        hok[hh] = (zh >= 0 && zh < 48);
        hcl[hh] = min(max(zh, 0), 47) * 48 * 64;
    }

    // 3 accumulator sets, aid == m (no rotation at DPB=3)
    float4 acc[3][4];
    #pragma unroll
    for (int a = 0; a < 3; ++a)
        #pragma unroll
        for (int r = 0; r < 4; ++r) acc[a][r] = make_float4(0.f, 0.f, 0.f, 0.f);

    float4 xvA[6], xvB[6];

    #pragma unroll
    for (int k = 0; k < 5; ++k) {
        int s = d0 - 1 + k;                    // slab depth
        bool s_ok = (s >= 0) && (s < 48);      // block-uniform

        // ---- conv: hh-pipelined direct global loads ----
        if (s_ok) {
            const float* dp = x + ((long)(b * 48 + s) * 48 * 48) * 64 + c0;

            // issue phase-0 loads
            {
                const float* rowp = dp + hcl[0];
                #pragma unroll
                for (int p = 0; p < 6; ++p)
                    xvA[p] = *(const float4*)(rowp + wcl[p]);
            }

            #pragma unroll
            for (int hh = 0; hh < 3; ++hh) {
                // issue phase hh+1 loads into the other buffer
                if (hh < 2) {
                    const float* rowp = dp + hcl[hh + 1];
                    if (hh == 0) {
                        #pragma unroll
                        for (int p = 0; p < 6; ++p)
                            xvB[p] = *(const float4*)(rowp + wcl[p]);
                    } else {
                        #pragma unroll
                        for (int p = 0; p < 6; ++p)
                            xvA[p] = *(const float4*)(rowp + wcl[p]);
                    }
                }

                if (hok[hh]) {                 // wave-uniform branch
                    float4 xv[6];
                    #pragma unroll
                    for (int p = 0; p < 6; ++p)
                        xv[p] = (hh == 1) ? xvB[p] : xvA[p];   // static select
                    xv[0].x *= mwL; xv[0].y *= mwL; xv[0].z *= mwL; xv[0].w *= mwL;
                    xv[5].x *= mwR; xv[5].y *= mwR; xv[5].z *= mwR; xv[5].w *= mwR;
                    #pragma unroll
                    for (int m = 0; m < 3; ++m) {
                        if (m >= k - 2 && m <= k) {      // folds at compile time
                            const int wz = k - m;        // weight z-tap
                            #pragma unroll
                            for (int ww = 0; ww < 3; ++ww) {
                                const float4 wvv = *(const float4*)(&wS[((wz * 3 + hh) * 3 + ww) * 64 + c0]);
                                #pragma unroll
                                for (int r = 0; r < 4; ++r) {
                                    acc[m][r].x += xv[r + ww].x * wvv.x;
                                    acc[m][r].y += xv[r + ww].y * wvv.y;
                                    acc[m][r].z += xv[r + ww].z * wvv.z;
                                    acc[m][r].w += xv[r + ww].w * wvv.w;
                                }
                            }
                        }
                    }
                }
            }
        }

        // ---- finish output m = k-2 (m = 0,1,2 at k = 2,3,4) ----
        if (k >= 2) {
            const int m = k - 2;
            const int bu = m & 1;              // yS buffer

            // BN1 + ReLU + bf16 -> yS[bu]
            {
                float4 s1 = *(const float4*)(&sS[c0]);
                float4 t1 = *(const float4*)(&tS[c0]);
                #pragma unroll
                for (int r = 0; r < 4; ++r) {
                    ushort4 o;
                    o.x = f2bf(fmaxf(acc[m][r].x * s1.x + t1.x, 0.f));
                    o.y = f2bf(fmaxf(acc[m][r].y * s1.y + t1.y, 0.f));
                    o.z = f2bf(fmaxf(acc[m][r].z * s1.z + t1.z, 0.f));
                    o.w = f2bf(fmaxf(acc[m][r].w * s1.w + t1.w, 0.f));
                    *(ushort4*)(&yS[bu][(ty * 4 + r) * 72 + c0]) = o;
                }
            }
            __syncthreads();   // RAW: yS[bu] visible.  (WAR across buffers is
                               // fenced by the NEXT iteration's barrier.)

            // GEMM: 4 waves, wave = 16 rows x 128 cols, K=64, 2 MFMA k-steps
            const short8 a0 = *(const short8*)(&yS[bu][(wv * 16 + lrow) * 72 + quad * 8]);
            const short8 a1 = *(const short8*)(&yS[bu][(wv * 16 + lrow) * 72 + 32 + quad * 8]);

            v4f gacc[8];
            #pragma unroll
            for (int nn = 0; nn < 8; ++nn) gacc[nn] = (v4f){0.f, 0.f, 0.f, 0.f};

            #pragma unroll
            for (int nn = 0; nn < 8; ++nn) {
                short8 b0 = *(const short8*)(Wt + ((nn * 2 + 0) * 64 + lane) * 8);
                short8 b1 = *(const short8*)(Wt + ((nn * 2 + 1) * 64 + lane) * 8);
                gacc[nn] = __builtin_amdgcn_mfma_f32_16x16x32_bf16(a0, b0, gacc[nn], 0, 0, 0);
                gacc[nn] = __builtin_amdgcn_mfma_f32_16x16x32_bf16(a1, b1, gacc[nn], 0, 0, 0);
            }

            // BN2 + ReLU epilogue, non-temporal stores (keep L2 for x).
            int d = d0 + m;
            long base_out = ((((long)b * 48 + d) * 48 + (h0 + wv)) * 48 + w0) * 128;
            #pragma unroll
            for (int nn = 0; nn < 8; ++nn) {
                int f = nn * 16 + lrow;
                float sf = s2S[f];
                float tf = t2S[f];
                #pragma unroll
                for (int r = 0; r < 4; ++r) {
                    float v = fmaxf(gacc[nn][r] * sf + tf, 0.f);
                    __builtin_nontemporal_store(v, &out[base_out + (quad * 4 + r) * 128 + f]);
                }
            }
        }
    }
}

// ---------------------------------------------------------------------------
extern "C" void kernel_launch(void* const* d_in, const int* in_sizes, int n_in,
                              void* d_out, int out_size, void* d_ws, size_t ws_size,
                              hipStream_t stream)
{
    const float* x   = (const float*)d_in[0];
    const float* dwk = (const float*)d_in[1];
    const float* dwb = (const float*)d_in[2];
    const float* g1  = (const float*)d_in[3];
    const float* b1  = (const float*)d_in[4];
    const float* m1  = (const float*)d_in[5];
    const float* v1  = (const float*)d_in[6];
    const float* pw  = (const float*)d_in[7];
    const float* pwb = (const float*)d_in[8];
    const float* g2  = (const float*)d_in[9];
    const float* b2  = (const float*)d_in[10];
    const float* m2  = (const float*)d_in[11];
    const float* v2  = (const float*)d_in[12];

    float* outp = (float*)d_out;

    float* scale1 = (float*)d_ws;
    float* shift1 = scale1 + 64;
    float* s2     = scale1 + 128;
    float* t2     = scale1 + 256;
    unsigned short* Wt = (unsigned short*)((char*)d_ws + 2048);

    hipLaunchKernelGGL(prep_kernel, dim3(32), dim3(256), 0, stream,
                       dwb, g1, b1, m1, v1, pw, pwb, g2, b2, m2, v2,
                       scale1, shift1, s2, t2, Wt);

    hipLaunchKernelGGL(fused_kernel, dim3(1152), dim3(256), 0, stream,
                       x, dwk, scale1, shift1, Wt, s2, t2, outp);
}

// Round 11
// 229.248 us; speedup vs baseline: 1.0138x; 1.0138x over previous
//
#include <hip/hip_runtime.h>
#include <hip/hip_bf16.h>

#define EPS 1e-3f

typedef __attribute__((ext_vector_type(8))) short short8;
typedef __attribute__((ext_vector_type(4))) float v4f;

__device__ __forceinline__ unsigned short f2bf(float f) {
    unsigned int u = __float_as_uint(f);
    unsigned int r = (u + 0x7fffu + ((u >> 16) & 1u)) >> 16;
    return (unsigned short)r;
}

// ---------------------------------------------------------------------------
// Prep: fold biases + BN into per-channel affine; transpose pw_kernel into
// bf16 MFMA B-fragment layout.  (unchanged)
// ---------------------------------------------------------------------------
__global__ __launch_bounds__(256) void prep_kernel(
    const float* __restrict__ dwb,
    const float* __restrict__ g1, const float* __restrict__ b1,
    const float* __restrict__ m1, const float* __restrict__ v1,
    const float* __restrict__ pw, const float* __restrict__ pwb,
    const float* __restrict__ g2, const float* __restrict__ b2,
    const float* __restrict__ m2, const float* __restrict__ v2,
    float* __restrict__ scale1, float* __restrict__ shift1,
    float* __restrict__ s2, float* __restrict__ t2,
    unsigned short* __restrict__ Wt)
{
    int tid = threadIdx.x;
    if (blockIdx.x == 0) {
        if (tid < 64) {
            float inv = g1[tid] * rsqrtf(v1[tid] + EPS);
            scale1[tid] = inv;
            shift1[tid] = dwb[tid] * inv + b1[tid] - m1[tid] * inv;
        }
        if (tid < 128) {
            float inv = g2[tid] * rsqrtf(v2[tid] + EPS);
            s2[tid] = inv;
            t2[tid] = pwb[tid] * inv + b2[tid] - m2[tid] * inv;
        }
    }
    int idx = blockIdx.x * 256 + tid;      // 0..8191
    int j     = idx & 7;
    int lane  = (idx >> 3) & 63;
    int kstep = (idx >> 9) & 1;
    int ntile = idx >> 10;                 // 0..7
    int k = kstep * 32 + (lane >> 4) * 8 + j;
    int f = ntile * 16 + (lane & 15);
    Wt[idx] = f2bf(pw[k * 128 + f]);
}

// ---------------------------------------------------------------------------
// Fused kernel, store-decoupled pipeline v6.
// R10 post-mortem: NT stores caused partial-line RMW (+69MB traffic) ->
// reverted.  Residual 72us theory: __syncthreads drains vmcnt(0) incl. the
// previous finish's 32 output stores (in-order vmcnt) -> every block waits
// for HBM store-acks 3x per block before issuing the next slab's loads.
// Fix: (1) finish pipelined one k-step behind conv (GEMM(m=k-3) runs FIRST
// in iter k, stores issued before slab-k loads -> both fly concurrently);
// (2) raw  s_waitcnt lgkmcnt(0) + s_barrier + sched_barrier  instead of
// __syncthreads (only yS LDS traffic is fenced; stores cross the barrier);
// (3) sched_barrier(0) fences pin issue order (stores -> loads -> FMAs).
// Structure: DPB=3, grid 1152, direct-global conv (clamped + masks),
// yS double-buffered, launch_bounds(256,3), plain stores.  LDS 27.1 KB.
// ---------------------------------------------------------------------------
__global__ __launch_bounds__(256, 3) void fused_kernel(
    const float* __restrict__ x,
    const float* __restrict__ wgt,          // (3,3,3,1,64)
    const float* __restrict__ scale1,
    const float* __restrict__ shift1,
    const unsigned short* __restrict__ Wt,  // bf16 B-fragments (16 KB)
    const float* __restrict__ s2,
    const float* __restrict__ t2,
    float* __restrict__ out)
{
    __shared__ float wS[27 * 64];              // 6912 B
    __shared__ float sS[64];
    __shared__ float tS[64];
    __shared__ float s2S[128];
    __shared__ float t2S[128];
    __shared__ unsigned short yS[2][64 * 72];  // 2 x 9216 B

    int tid = threadIdx.x;
    for (int i = tid; i < 27 * 64; i += 256) wS[i] = wgt[i];
    if (tid < 64) { sS[tid] = scale1[tid]; tS[tid] = shift1[tid]; }
    if (tid < 128) { s2S[tid] = s2[tid]; t2S[tid] = t2[tid]; }
    __syncthreads();

    // XCD-aware decode: 1152 blocks = 8 xcd * 144; each XCD owns 4
    // consecutive bdg groups (contiguous 12-deep d range -> L2-shared halos)
    int n   = blockIdx.x;
    int g   = (n & 7) * 144 + (n >> 3);
    int bdg = g / 36;              // 0..31 = b*16 + dgrp
    int hw  = g % 36;
    int b    = bdg >> 4;
    int dgrp = bdg & 15;
    int d0   = dgrp * 3;
    int w0  = (hw % 3) * 16;
    int h0  = (hw / 3) * 4;

    int tx = tid & 15;            // channel group
    int ty = tid >> 4;            // 0..15
    int c0 = tx * 4;
    int wq = ty & 3;
    int rh = ty >> 2;             // == wave id -> h is wave-uniform

    int wv   = tid >> 6;
    int lane = tid & 63;
    int lrow = lane & 15;
    int quad = lane >> 4;

    // ---- per-thread invariant conv addressing (clamped) ----
    int w0t = w0 + wq * 4;
    float mwL = (w0t >= 1)  ? 1.f : 0.f;   // window p=0 (zw = w0t-1)
    float mwR = (w0t <= 43) ? 1.f : 0.f;   // window p=5 (zw = w0t+4)
    int wcl[6];
    #pragma unroll
    for (int p = 0; p < 6; ++p)
        wcl[p] = min(max(w0t - 1 + p, 0), 47) * 64;

    int h = h0 + rh;
    bool hok[3];
    int  hcl[3];
    #pragma unroll
    for (int hh = 0; hh < 3; ++hh) {
        int zh = h + hh - 1;
        hok[hh] = (zh >= 0 && zh < 48);
        hcl[hh] = min(max(zh, 0), 47) * 48 * 64;
    }

    // 3 accumulator sets, aid == m (no rotation at DPB=3)
    float4 acc[3][4];
    #pragma unroll
    for (int a = 0; a < 3; ++a)
        #pragma unroll
        for (int r = 0; r < 4; ++r) acc[a][r] = make_float4(0.f, 0.f, 0.f, 0.f);

    #pragma unroll
    for (int k = 0; k < 6; ++k) {
        int s = d0 - 1 + k;                    // slab depth
        bool s_ok = (k <= 4) && (s >= 0) && (s < 48);   // block-uniform

        // ---- 1. GEMM + BN2 + stores for output m = k-3 (one k behind) ----
        // Stores are issued BEFORE this iter's slab loads and are never
        // drained by a barrier -- they retire while later work proceeds.
        if (k >= 3) {
            const int m = k - 3;
            const int bu = m & 1;              // yS buffer (written at iter k-1)

            const short8 a0 = *(const short8*)(&yS[bu][(wv * 16 + lrow) * 72 + quad * 8]);
            const short8 a1 = *(const short8*)(&yS[bu][(wv * 16 + lrow) * 72 + 32 + quad * 8]);

            v4f gacc[8];
            #pragma unroll
            for (int nn = 0; nn < 8; ++nn) gacc[nn] = (v4f){0.f, 0.f, 0.f, 0.f};

            #pragma unroll
            for (int nn = 0; nn < 8; ++nn) {
                short8 b0 = *(const short8*)(Wt + ((nn * 2 + 0) * 64 + lane) * 8);
                short8 b1 = *(const short8*)(Wt + ((nn * 2 + 1) * 64 + lane) * 8);
                gacc[nn] = __builtin_amdgcn_mfma_f32_16x16x32_bf16(a0, b0, gacc[nn], 0, 0, 0);
                gacc[nn] = __builtin_amdgcn_mfma_f32_16x16x32_bf16(a1, b1, gacc[nn], 0, 0, 0);
            }

            int d = d0 + m;
            long base_out = ((((long)b * 48 + d) * 48 + (h0 + wv)) * 48 + w0) * 128;
            #pragma unroll
            for (int nn = 0; nn < 8; ++nn) {
                int f = nn * 16 + lrow;
                float sf = s2S[f];
                float tf = t2S[f];
                #pragma unroll
                for (int r = 0; r < 4; ++r) {
                    float v = fmaxf(gacc[nn][r] * sf + tf, 0.f);
                    out[base_out + (quad * 4 + r) * 128 + f] = v;
                }
            }
        }
        __builtin_amdgcn_sched_barrier(0);   // stores issued before loads

        // ---- 2. issue ALL 18 slab-k loads (fly alongside the stores) ----
        float4 xv[18];
        if (s_ok) {
            const float* dp = x + ((long)(b * 48 + s) * 48 * 48) * 64 + c0;
            #pragma unroll
            for (int hh = 0; hh < 3; ++hh) {
                const float* rowp = dp + hcl[hh];
                #pragma unroll
                for (int p = 0; p < 6; ++p)
                    xv[hh * 6 + p] = *(const float4*)(rowp + wcl[p]);
            }
        }
        __builtin_amdgcn_sched_barrier(0);   // loads issued before FMAs

        // ---- 3. conv FMAs (wait only on this iter's loads; stores are
        //         older in the in-order vmcnt queue, so no extra stall) ----
        if (s_ok) {
            #pragma unroll
            for (int hh = 0; hh < 3; ++hh) {
                if (hok[hh]) {                 // wave-uniform branch
                    float4 xm[6];
                    #pragma unroll
                    for (int p = 0; p < 6; ++p) xm[p] = xv[hh * 6 + p];
                    xm[0].x *= mwL; xm[0].y *= mwL; xm[0].z *= mwL; xm[0].w *= mwL;
                    xm[5].x *= mwR; xm[5].y *= mwR; xm[5].z *= mwR; xm[5].w *= mwR;
                    #pragma unroll
                    for (int m = 0; m < 3; ++m) {
                        if (m >= k - 2 && m <= k) {      // folds at compile time
                            const int wz = k - m;        // weight z-tap
                            #pragma unroll
                            for (int ww = 0; ww < 3; ++ww) {
                                const float4 wvv = *(const float4*)(&wS[((wz * 3 + hh) * 3 + ww) * 64 + c0]);
                                #pragma unroll
                                for (int r = 0; r < 4; ++r) {
                                    acc[m][r].x += xm[r + ww].x * wvv.x;
                                    acc[m][r].y += xm[r + ww].y * wvv.y;
                                    acc[m][r].z += xm[r + ww].z * wvv.z;
                                    acc[m][r].w += xm[r + ww].w * wvv.w;
                                }
                            }
                        }
                    }
                }
            }
        }

        // ---- 4. BN1 + ReLU + bf16 -> yS for output m = k-2, then an
        //         LDS-only barrier (lgkmcnt(0) + raw s_barrier): the
        //         output stores CROSS this barrier unharmed. ----
        if (k >= 2 && k <= 4) {
            const int m = k - 2;
            const int bu = m & 1;
            float4 s1 = *(const float4*)(&sS[c0]);
            float4 t1 = *(const float4*)(&tS[c0]);
            #pragma unroll
            for (int r = 0; r < 4; ++r) {
                ushort4 o;
                o.x = f2bf(fmaxf(acc[m][r].x * s1.x + t1.x, 0.f));
                o.y = f2bf(fmaxf(acc[m][r].y * s1.y + t1.y, 0.f));
                o.z = f2bf(fmaxf(acc[m][r].z * s1.z + t1.z, 0.f));
                o.w = f2bf(fmaxf(acc[m][r].w * s1.w + t1.w, 0.f));
                *(ushort4*)(&yS[bu][(ty * 4 + r) * 72 + c0]) = o;
            }
            asm volatile("s_waitcnt lgkmcnt(0)" ::: "memory");
            __builtin_amdgcn_s_barrier();
            __builtin_amdgcn_sched_barrier(0);
        }
    }
}

// ---------------------------------------------------------------------------
extern "C" void kernel_launch(void* const* d_in, const int* in_sizes, int n_in,
                              void* d_out, int out_size, void* d_ws, size_t ws_size,
                              hipStream_t stream)
{
    const float* x   = (const float*)d_in[0];
    const float* dwk = (const float*)d_in[1];
    const float* dwb = (const float*)d_in[2];
    const float* g1  = (const float*)d_in[3];
    const float* b1  = (const float*)d_in[4];
    const float* m1  = (const float*)d_in[5];
    const float* v1  = (const float*)d_in[6];
    const float* pw  = (const float*)d_in[7];
    const float* pwb = (const float*)d_in[8];
    const float* g2  = (const float*)d_in[9];
    const float* b2  = (const float*)d_in[10];
    const float* m2  = (const float*)d_in[11];
    const float* v2  = (const float*)d_in[12];

    float* outp = (float*)d_out;

    float* scale1 = (float*)d_ws;
    float* shift1 = scale1 + 64;
    float* s2     = scale1 + 128;
    float* t2     = scale1 + 256;
    unsigned short* Wt = (unsigned short*)((char*)d_ws + 2048);

    hipLaunchKernelGGL(prep_kernel, dim3(32), dim3(256), 0, stream,
                       dwb, g1, b1, m1, v1, pw, pwb, g2, b2, m2, v2,
                       scale1, shift1, s2, t2, Wt);

    hipLaunchKernelGGL(fused_kernel, dim3(1152), dim3(256), 0, stream,
                       x, dwk, scale1, shift1, Wt, s2, t2, outp);
}

// Round 12
// 209.057 us; speedup vs baseline: 1.1117x; 1.0966x over previous
//
#include <hip/hip_runtime.h>
#include <hip/hip_bf16.h>

#define EPS 1e-3f

typedef __attribute__((ext_vector_type(8))) short short8;
typedef __attribute__((ext_vector_type(4))) float v4f;

__device__ __forceinline__ unsigned short f2bf(float f) {
    unsigned int u = __float_as_uint(f);
    unsigned int r = (u + 0x7fffu + ((u >> 16) & 1u)) >> 16;
    return (unsigned short)r;
}

// ---------------------------------------------------------------------------
// Prep: fold biases + BN into per-channel affine; transpose pw_kernel into
// bf16 MFMA B-fragment layout.  (unchanged)
// ---------------------------------------------------------------------------
__global__ __launch_bounds__(256) void prep_kernel(
    const float* __restrict__ dwb,
    const float* __restrict__ g1, const float* __restrict__ b1,
    const float* __restrict__ m1, const float* __restrict__ v1,
    const float* __restrict__ pw, const float* __restrict__ pwb,
    const float* __restrict__ g2, const float* __restrict__ b2,
    const float* __restrict__ m2, const float* __restrict__ v2,
    float* __restrict__ scale1, float* __restrict__ shift1,
    float* __restrict__ s2, float* __restrict__ t2,
    unsigned short* __restrict__ Wt)
{
    int tid = threadIdx.x;
    if (blockIdx.x == 0) {
        if (tid < 64) {
            float inv = g1[tid] * rsqrtf(v1[tid] + EPS);
            scale1[tid] = inv;
            shift1[tid] = dwb[tid] * inv + b1[tid] - m1[tid] * inv;
        }
        if (tid < 128) {
            float inv = g2[tid] * rsqrtf(v2[tid] + EPS);
            s2[tid] = inv;
            t2[tid] = pwb[tid] * inv + b2[tid] - m2[tid] * inv;
        }
    }
    int idx = blockIdx.x * 256 + tid;      // 0..8191
    int j     = idx & 7;
    int lane  = (idx >> 3) & 63;
    int kstep = (idx >> 9) & 1;
    int ntile = idx >> 10;                 // 0..7
    int k = kstep * 32 + (lane >> 4) * 8 + j;
    int f = ntile * 16 + (lane & 15);
    Wt[idx] = f2bf(pw[k * 128 + f]);
}

// ---------------------------------------------------------------------------
// Fused kernel, barrier-free wave-pipeline v7.
// KEY INSIGHT (R11 audit): yS is already wave-aligned -- wave wv writes BN1
// rows [wv*16, wv*16+16) and its GEMM reads exactly those rows.  There is NO
// cross-wave data sharing in the main loop, so every __syncthreads there was
// pure lock-step overhead: it forced all 4 waves to wait for the slowest
// wave's load phase, every iteration (per-iter 2.9us vs 0.7us VALU need).
// Change vs R9 (single lever): ALL main-loop barriers deleted; yS single-
// buffered (wave-private slices; within-wave LDS RAW/WAR is guaranteed by
// in-order DS execution + compiler lgkmcnt).  Waves become 4 independent
// conv->GEMM pipelines; the CU scheduler hides load latency by interleaving.
// R11's sched_barrier pinning (xv[18] live -> spill) reverted: body = R9.
// Structure: DPB=3, grid 1152, direct-global conv (clamped + masks),
// launch_bounds(256,3) (proven no-spill: VGPR ~80-84).  LDS 18.6 KB.
// ---------------------------------------------------------------------------
__global__ __launch_bounds__(256, 3) void fused_kernel(
    const float* __restrict__ x,
    const float* __restrict__ wgt,          // (3,3,3,1,64)
    const float* __restrict__ scale1,
    const float* __restrict__ shift1,
    const unsigned short* __restrict__ Wt,  // bf16 B-fragments (16 KB)
    const float* __restrict__ s2,
    const float* __restrict__ t2,
    float* __restrict__ out)
{
    __shared__ float wS[27 * 64];              // 6912 B
    __shared__ float sS[64];
    __shared__ float tS[64];
    __shared__ float s2S[128];
    __shared__ float t2S[128];
    __shared__ unsigned short yS[64 * 72];     // 9216 B, wave-private 16-row slices

    int tid = threadIdx.x;
    for (int i = tid; i < 27 * 64; i += 256) wS[i] = wgt[i];
    if (tid < 64) { sS[tid] = scale1[tid]; tS[tid] = shift1[tid]; }
    if (tid < 128) { s2S[tid] = s2[tid]; t2S[tid] = t2[tid]; }
    __syncthreads();   // the ONLY block-wide barrier (prologue weights)

    // XCD-aware decode: 1152 blocks = 8 xcd * 144; each XCD owns 4
    // consecutive bdg groups (contiguous 12-deep d range -> L2-shared halos)
    int n   = blockIdx.x;
    int g   = (n & 7) * 144 + (n >> 3);
    int bdg = g / 36;              // 0..31 = b*16 + dgrp
    int hw  = g % 36;
    int b    = bdg >> 4;
    int dgrp = bdg & 15;
    int d0   = dgrp * 3;
    int w0  = (hw % 3) * 16;
    int h0  = (hw / 3) * 4;

    int tx = tid & 15;            // channel group
    int ty = tid >> 4;            // 0..15
    int c0 = tx * 4;
    int wq = ty & 3;
    int rh = ty >> 2;             // == wave id -> h is wave-uniform

    int wv   = tid >> 6;
    int lane = tid & 63;
    int lrow = lane & 15;
    int quad = lane >> 4;

    // ---- per-thread invariant conv addressing (clamped) ----
    int w0t = w0 + wq * 4;
    float mwL = (w0t >= 1)  ? 1.f : 0.f;   // window p=0 (zw = w0t-1)
    float mwR = (w0t <= 43) ? 1.f : 0.f;   // window p=5 (zw = w0t+4)
    int wcl[6];
    #pragma unroll
    for (int p = 0; p < 6; ++p)
        wcl[p] = min(max(w0t - 1 + p, 0), 47) * 64;

    int h = h0 + rh;
    bool hok[3];
    int  hcl[3];
    #pragma unroll
    for (int hh = 0; hh < 3; ++hh) {
        int zh = h + hh - 1;
        hok[hh] = (zh >= 0 && zh < 48);
        hcl[hh] = min(max(zh, 0), 47) * 48 * 64;
    }

    // 3 accumulator sets, aid == m (no rotation at DPB=3)
    float4 acc[3][4];
    #pragma unroll
    for (int a = 0; a < 3; ++a)
        #pragma unroll
        for (int r = 0; r < 4; ++r) acc[a][r] = make_float4(0.f, 0.f, 0.f, 0.f);

    #pragma unroll
    for (int k = 0; k < 5; ++k) {
        int s = d0 - 1 + k;                    // slab depth
        bool s_ok = (s >= 0) && (s < 48);      // block-uniform

        // ---- conv: direct global loads (private, barrier-free) ----
        if (s_ok) {
            const float* dp = x + ((long)(b * 48 + s) * 48 * 48) * 64 + c0;
            #pragma unroll
            for (int hh = 0; hh < 3; ++hh) {
                if (hok[hh]) {                 // wave-uniform branch
                    const float* rowp = dp + hcl[hh];
                    float4 xv[6];
                    #pragma unroll
                    for (int p = 0; p < 6; ++p)
                        xv[p] = *(const float4*)(rowp + wcl[p]);
                    xv[0].x *= mwL; xv[0].y *= mwL; xv[0].z *= mwL; xv[0].w *= mwL;
                    xv[5].x *= mwR; xv[5].y *= mwR; xv[5].z *= mwR; xv[5].w *= mwR;
                    #pragma unroll
                    for (int m = 0; m < 3; ++m) {
                        if (m >= k - 2 && m <= k) {      // folds at compile time
                            const int wz = k - m;        // weight z-tap
                            #pragma unroll
                            for (int ww = 0; ww < 3; ++ww) {
                                const float4 wvv = *(const float4*)(&wS[((wz * 3 + hh) * 3 + ww) * 64 + c0]);
                                #pragma unroll
                                for (int r = 0; r < 4; ++r) {
                                    acc[m][r].x += xv[r + ww].x * wvv.x;
                                    acc[m][r].y += xv[r + ww].y * wvv.y;
                                    acc[m][r].z += xv[r + ww].z * wvv.z;
                                    acc[m][r].w += xv[r + ww].w * wvv.w;
                                }
                            }
                        }
                    }
                }
            }
        }

        // ---- finish output m = k-2 (wave-private, NO barriers) ----
        if (k >= 2) {
            const int m = k - 2;

            // BN1 + ReLU + bf16 -> this wave's own yS rows
            {
                float4 s1 = *(const float4*)(&sS[c0]);
                float4 t1 = *(const float4*)(&tS[c0]);
                #pragma unroll
                for (int r = 0; r < 4; ++r) {
                    ushort4 o;
                    o.x = f2bf(fmaxf(acc[m][r].x * s1.x + t1.x, 0.f));
                    o.y = f2bf(fmaxf(acc[m][r].y * s1.y + t1.y, 0.f));
                    o.z = f2bf(fmaxf(acc[m][r].z * s1.z + t1.z, 0.f));
                    o.w = f2bf(fmaxf(acc[m][r].w * s1.w + t1.w, 0.f));
                    *(ushort4*)(&yS[(ty * 4 + r) * 72 + c0]) = o;
                }
            }
            // within-wave RAW on yS: in-order DS + compiler lgkmcnt handles it

            // GEMM: this wave's 16 rows x 128 cols, K=64, 2 MFMA k-steps
            const short8 a0 = *(const short8*)(&yS[(wv * 16 + lrow) * 72 + quad * 8]);
            const short8 a1 = *(const short8*)(&yS[(wv * 16 + lrow) * 72 + 32 + quad * 8]);

            v4f gacc[8];
            #pragma unroll
            for (int nn = 0; nn < 8; ++nn) gacc[nn] = (v4f){0.f, 0.f, 0.f, 0.f};

            #pragma unroll
            for (int nn = 0; nn < 8; ++nn) {
                short8 b0 = *(const short8*)(Wt + ((nn * 2 + 0) * 64 + lane) * 8);
                short8 b1 = *(const short8*)(Wt + ((nn * 2 + 1) * 64 + lane) * 8);
                gacc[nn] = __builtin_amdgcn_mfma_f32_16x16x32_bf16(a0, b0, gacc[nn], 0, 0, 0);
                gacc[nn] = __builtin_amdgcn_mfma_f32_16x16x32_bf16(a1, b1, gacc[nn], 0, 0, 0);
            }

            // BN2 + ReLU epilogue. D: col=lane&15, row=quad*4+reg.
            int d = d0 + m;
            long base_out = ((((long)b * 48 + d) * 48 + (h0 + wv)) * 48 + w0) * 128;
            #pragma unroll
            for (int nn = 0; nn < 8; ++nn) {
                int f = nn * 16 + lrow;
                float sf = s2S[f];
                float tf = t2S[f];
                #pragma unroll
                for (int r = 0; r < 4; ++r) {
                    float v = fmaxf(gacc[nn][r] * sf + tf, 0.f);
                    out[base_out + (quad * 4 + r) * 128 + f] = v;
                }
            }
        }
    }
}

// ---------------------------------------------------------------------------
extern "C" void kernel_launch(void* const* d_in, const int* in_sizes, int n_in,
                              void* d_out, int out_size, void* d_ws, size_t ws_size,
                              hipStream_t stream)
{
    const float* x   = (const float*)d_in[0];
    const float* dwk = (const float*)d_in[1];
    const float* dwb = (const float*)d_in[2];
    const float* g1  = (const float*)d_in[3];
    const float* b1  = (const float*)d_in[4];
    const float* m1  = (const float*)d_in[5];
    const float* v1  = (const float*)d_in[6];
    const float* pw  = (const float*)d_in[7];
    const float* pwb = (const float*)d_in[8];
    const float* g2  = (const float*)d_in[9];
    const float* b2  = (const float*)d_in[10];
    const float* m2  = (const float*)d_in[11];
    const float* v2  = (const float*)d_in[12];

    float* outp = (float*)d_out;

    float* scale1 = (float*)d_ws;
    float* shift1 = scale1 + 64;
    float* s2     = scale1 + 128;
    float* t2     = scale1 + 256;
    unsigned short* Wt = (unsigned short*)((char*)d_ws + 2048);

    hipLaunchKernelGGL(prep_kernel, dim3(32), dim3(256), 0, stream,
                       dwb, g1, b1, m1, v1, pw, pwb, g2, b2, m2, v2,
                       scale1, shift1, s2, t2, Wt);

    hipLaunchKernelGGL(fused_kernel, dim3(1152), dim3(256), 0, stream,
                       x, dwk, scale1, shift1, Wt, s2, t2, outp);
}

// Round 13
// 196.493 us; speedup vs baseline: 1.1827x; 1.0639x over previous
//
#include <hip/hip_runtime.h>
#include <hip/hip_bf16.h>

#define EPS 1e-3f

typedef __attribute__((ext_vector_type(8))) short short8;
typedef __attribute__((ext_vector_type(4))) float v4f;

__device__ __forceinline__ unsigned short f2bf(float f) {
    unsigned int u = __float_as_uint(f);
    unsigned int r = (u + 0x7fffu + ((u >> 16) & 1u)) >> 16;
    return (unsigned short)r;
}

// ---------------------------------------------------------------------------
// Prep: fold biases + BN into per-channel affine; transpose pw_kernel into
// bf16 MFMA B-fragment layout.  (unchanged)
// ---------------------------------------------------------------------------
__global__ __launch_bounds__(256) void prep_kernel(
    const float* __restrict__ dwb,
    const float* __restrict__ g1, const float* __restrict__ b1,
    const float* __restrict__ m1, const float* __restrict__ v1,
    const float* __restrict__ pw, const float* __restrict__ pwb,
    const float* __restrict__ g2, const float* __restrict__ b2,
    const float* __restrict__ m2, const float* __restrict__ v2,
    float* __restrict__ scale1, float* __restrict__ shift1,
    float* __restrict__ s2, float* __restrict__ t2,
    unsigned short* __restrict__ Wt)
{
    int tid = threadIdx.x;
    if (blockIdx.x == 0) {
        if (tid < 64) {
            float inv = g1[tid] * rsqrtf(v1[tid] + EPS);
            scale1[tid] = inv;
            shift1[tid] = dwb[tid] * inv + b1[tid] - m1[tid] * inv;
        }
        if (tid < 128) {
            float inv = g2[tid] * rsqrtf(v2[tid] + EPS);
            s2[tid] = inv;
            t2[tid] = pwb[tid] * inv + b2[tid] - m2[tid] * inv;
        }
    }
    int idx = blockIdx.x * 256 + tid;      // 0..8191
    int j     = idx & 7;
    int lane  = (idx >> 3) & 63;
    int kstep = (idx >> 9) & 1;
    int ntile = idx >> 10;                 // 0..7
    int k = kstep * 32 + (lane >> 4) * 8 + j;
    int f = ntile * 16 + (lane & 15);
    Wt[idx] = f2bf(pw[k * 128 + f]);
}

// ---------------------------------------------------------------------------
// Fused kernel, lockstep-combined v8.
// R12 lesson: lockstep barriers HELP (waves aligned on the same slab ->
// L2-coalesced halo loads; barrier-free drifted and lost 18%).  So combine
// the two best proven configs instead:
//   - DPB=6 / grid 576 (R6): 1.33x slab re-reads, 8 iters / 6 outputs.
//   - yS double-buffer -> ONE barrier per finish (R9's proven scheme).
//   - NEW: Wt staged to LDS once (16 KB) -- GEMM's 16 B-fragment loads go
//     from ~L2 latency to LDS latency, off the post-barrier critical path.
// Conv stays direct-from-global (clamped + masks, private).
// launch_bounds(256,3) (proven no-spill).  LDS 43.3 KB.
// ---------------------------------------------------------------------------
__global__ __launch_bounds__(256, 3) void fused_kernel(
    const float* __restrict__ x,
    const float* __restrict__ wgt,          // (3,3,3,1,64)
    const float* __restrict__ scale1,
    const float* __restrict__ shift1,
    const unsigned short* __restrict__ Wt,  // bf16 B-fragments (16 KB)
    const float* __restrict__ s2,
    const float* __restrict__ t2,
    float* __restrict__ out)
{
    __shared__ float wS[27 * 64];              // 6912 B
    __shared__ float sS[64];
    __shared__ float tS[64];
    __shared__ float s2S[128];
    __shared__ float t2S[128];
    __shared__ unsigned short wtS[8192];       // 16384 B
    __shared__ unsigned short yS[2][64 * 72];  // 2 x 9216 B

    int tid = threadIdx.x;
    for (int i = tid; i < 27 * 64; i += 256) wS[i] = wgt[i];
    #pragma unroll
    for (int i = 0; i < 4; ++i)
        ((float4*)wtS)[i * 256 + tid] = ((const float4*)Wt)[i * 256 + tid];
    if (tid < 64) { sS[tid] = scale1[tid]; tS[tid] = shift1[tid]; }
    if (tid < 128) { s2S[tid] = s2[tid]; t2S[tid] = t2[tid]; }
    __syncthreads();

    // XCD-aware decode: 576 blocks = 8 xcd * 72 (bijective; each XCD owns a
    // contiguous range -> d-halo slabs L2-shared)
    int n   = blockIdx.x;
    int g   = (n & 7) * 72 + (n >> 3);
    int bdg = g / 36;              // 0..15 = b*8 + dgrp
    int hw  = g % 36;
    int b    = bdg >> 3;
    int dgrp = bdg & 7;
    int d0   = dgrp * 6;
    int w0  = (hw % 3) * 16;
    int h0  = (hw / 3) * 4;

    int tx = tid & 15;            // channel group
    int ty = tid >> 4;            // 0..15
    int c0 = tx * 4;
    int wq = ty & 3;
    int rh = ty >> 2;             // == wave id -> h is wave-uniform

    int wv   = tid >> 6;
    int lane = tid & 63;
    int lrow = lane & 15;
    int quad = lane >> 4;

    // ---- per-thread invariant conv addressing (clamped) ----
    int w0t = w0 + wq * 4;
    float mwL = (w0t >= 1)  ? 1.f : 0.f;   // window p=0 (zw = w0t-1)
    float mwR = (w0t <= 43) ? 1.f : 0.f;   // window p=5 (zw = w0t+4)
    int wcl[6];
    #pragma unroll
    for (int p = 0; p < 6; ++p)
        wcl[p] = min(max(w0t - 1 + p, 0), 47) * 64;

    int h = h0 + rh;
    bool hok[3];
    int  hcl[3];
    #pragma unroll
    for (int hh = 0; hh < 3; ++hh) {
        int zh = h + hh - 1;
        hok[hh] = (zh >= 0 && zh < 48);
        hcl[hh] = min(max(zh, 0), 47) * 48 * 64;
    }

    // 3 rotating accumulator sets (aid = m % 3)
    float4 acc[3][4];
    #pragma unroll
    for (int a = 0; a < 3; ++a)
        #pragma unroll
        for (int r = 0; r < 4; ++r) acc[a][r] = make_float4(0.f, 0.f, 0.f, 0.f);

    #pragma unroll
    for (int k = 0; k < 8; ++k) {
        int s = d0 - 1 + k;                    // slab depth
        bool s_ok = (s >= 0) && (s < 48);      // block-uniform

        // ---- conv: direct global loads (private, lockstep via barrier) ----
        if (s_ok) {
            const float* dp = x + ((long)(b * 48 + s) * 48 * 48) * 64 + c0;
            #pragma unroll
            for (int hh = 0; hh < 3; ++hh) {
                if (hok[hh]) {                 // wave-uniform branch
                    const float* rowp = dp + hcl[hh];
                    float4 xv[6];
                    #pragma unroll
                    for (int p = 0; p < 6; ++p)
                        xv[p] = *(const float4*)(rowp + wcl[p]);
                    xv[0].x *= mwL; xv[0].y *= mwL; xv[0].z *= mwL; xv[0].w *= mwL;
                    xv[5].x *= mwR; xv[5].y *= mwR; xv[5].z *= mwR; xv[5].w *= mwR;
                    #pragma unroll
                    for (int m = 0; m < 6; ++m) {
                        if (m >= k - 2 && m <= k) {      // folds at compile time
                            const int wz  = k - m;       // weight z-tap
                            const int aid = m % 3;
                            #pragma unroll
                            for (int ww = 0; ww < 3; ++ww) {
                                const float4 wvv = *(const float4*)(&wS[((wz * 3 + hh) * 3 + ww) * 64 + c0]);
                                #pragma unroll
                                for (int r = 0; r < 4; ++r) {
                                    acc[aid][r].x += xv[r + ww].x * wvv.x;
                                    acc[aid][r].y += xv[r + ww].y * wvv.y;
                                    acc[aid][r].z += xv[r + ww].z * wvv.z;
                                    acc[aid][r].w += xv[r + ww].w * wvv.w;
                                }
                            }
                        }
                    }
                }
            }
        }

        // ---- finish output m = k-2 (ONE barrier per finish) ----
        if (k >= 2) {
            const int m   = k - 2;
            const int aid = m % 3;
            const int bu  = m & 1;             // yS buffer

            // BN1 + ReLU + bf16 -> yS[bu]; recycle acc[aid]
            {
                float4 s1 = *(const float4*)(&sS[c0]);
                float4 t1 = *(const float4*)(&tS[c0]);
                #pragma unroll
                for (int r = 0; r < 4; ++r) {
                    ushort4 o;
                    o.x = f2bf(fmaxf(acc[aid][r].x * s1.x + t1.x, 0.f));
                    o.y = f2bf(fmaxf(acc[aid][r].y * s1.y + t1.y, 0.f));
                    o.z = f2bf(fmaxf(acc[aid][r].z * s1.z + t1.z, 0.f));
                    o.w = f2bf(fmaxf(acc[aid][r].w * s1.w + t1.w, 0.f));
                    *(ushort4*)(&yS[bu][(ty * 4 + r) * 72 + c0]) = o;
                    acc[aid][r] = make_float4(0.f, 0.f, 0.f, 0.f);
                }
            }
            __syncthreads();   // RAW: yS[bu] visible.  WAR on yS[bu] (next
                               // write at iter k+2) is fenced by iter k+1's
                               // barrier -- scheme proven in R7/R8/R9.

            // GEMM: 4 waves, wave = 16 rows x 128 cols, K=64, 2 MFMA k-steps
            const short8 a0 = *(const short8*)(&yS[bu][(wv * 16 + lrow) * 72 + quad * 8]);
            const short8 a1 = *(const short8*)(&yS[bu][(wv * 16 + lrow) * 72 + 32 + quad * 8]);

            v4f gacc[8];
            #pragma unroll
            for (int nn = 0; nn < 8; ++nn) gacc[nn] = (v4f){0.f, 0.f, 0.f, 0.f};

            #pragma unroll
            for (int nn = 0; nn < 8; ++nn) {
                short8 b0 = *(const short8*)(&wtS[((nn * 2 + 0) * 64 + lane) * 8]);
                short8 b1 = *(const short8*)(&wtS[((nn * 2 + 1) * 64 + lane) * 8]);
                gacc[nn] = __builtin_amdgcn_mfma_f32_16x16x32_bf16(a0, b0, gacc[nn], 0, 0, 0);
                gacc[nn] = __builtin_amdgcn_mfma_f32_16x16x32_bf16(a1, b1, gacc[nn], 0, 0, 0);
            }

            // BN2 + ReLU epilogue. D: col=lane&15, row=quad*4+reg.
            int d = d0 + m;
            long base_out = ((((long)b * 48 + d) * 48 + (h0 + wv)) * 48 + w0) * 128;
            #pragma unroll
            for (int nn = 0; nn < 8; ++nn) {
                int f = nn * 16 + lrow;
                float sf = s2S[f];
                float tf = t2S[f];
                #pragma unroll
                for (int r = 0; r < 4; ++r) {
                    float v = fmaxf(gacc[nn][r] * sf + tf, 0.f);
                    out[base_out + (quad * 4 + r) * 128 + f] = v;
                }
            }
        }
    }
}

// ---------------------------------------------------------------------------
extern "C" void kernel_launch(void* const* d_in, const int* in_sizes, int n_in,
                              void* d_out, int out_size, void* d_ws, size_t ws_size,
                              hipStream_t stream)
{
    const float* x   = (const float*)d_in[0];
    const float* dwk = (const float*)d_in[1];
    const float* dwb = (const float*)d_in[2];
    const float* g1  = (const float*)d_in[3];
    const float* b1  = (const float*)d_in[4];
    const float* m1  = (const float*)d_in[5];
    const float* v1  = (const float*)d_in[6];
    const float* pw  = (const float*)d_in[7];
    const float* pwb = (const float*)d_in[8];
    const float* g2  = (const float*)d_in[9];
    const float* b2  = (const float*)d_in[10];
    const float* m2  = (const float*)d_in[11];
    const float* v2  = (const float*)d_in[12];

    float* outp = (float*)d_out;

    float* scale1 = (float*)d_ws;
    float* shift1 = scale1 + 64;
    float* s2     = scale1 + 128;
    float* t2     = scale1 + 256;
    unsigned short* Wt = (unsigned short*)((char*)d_ws + 2048);

    hipLaunchKernelGGL(prep_kernel, dim3(32), dim3(256), 0, stream,
                       dwb, g1, b1, m1, v1, pw, pwb, g2, b2, m2, v2,
                       scale1, shift1, s2, t2, Wt);

    hipLaunchKernelGGL(fused_kernel, dim3(576), dim3(256), 0, stream,
                       x, dwk, scale1, shift1, Wt, s2, t2, outp);
}